// Round 1
// baseline (1714.136 us; speedup 1.0000x reference)
//
#include <hip/hip_runtime.h>
#include <math.h>

constexpr int NN = 50000;
constexpr int NE = 600000;
constexpr int NG = 256;
constexpr float kBnEps = 1e-5f;
constexpr float kSlope = 0.2f;

// ---------------- input projection: h0 = relu(x @ W_in + b_in) ----------------
__global__ __launch_bounds__(256) void k_input_proj(
    const float* __restrict__ x, const float* __restrict__ W,
    const float* __restrict__ b, float* __restrict__ h0)
{
    __shared__ float Wl[64 * 64];
    __shared__ float bl[64];
    int tid = threadIdx.x;
    for (int i = tid; i < 64 * 64; i += 256) Wl[i] = W[i];
    if (tid < 64) bl[tid] = b[tid];
    __syncthreads();
    int lane = tid & 63, wave = tid >> 6;
    int row = blockIdx.x * 4 + wave;
    if (row >= NN) return;
    float xv = x[(size_t)row * 64 + lane];
    float acc = bl[lane];
    #pragma unroll
    for (int k = 0; k < 64; ++k) {
        float hb = __shfl(xv, k, 64);
        acc = fmaf(hb, Wl[k * 64 + lane], acc);
    }
    h0[(size_t)row * 64 + lane] = fmaxf(acc, 0.f);
}

// ---------------- counting sort of edges by dst ----------------
__global__ __launch_bounds__(256) void k_hist(const int* __restrict__ dst, int* __restrict__ cnt)
{
    int e = blockIdx.x * 256 + threadIdx.x;
    if (e < NE) atomicAdd(&cnt[dst[e]], 1);
}

__global__ __launch_bounds__(1024) void k_scan(const int* __restrict__ cnt,
                                               int* __restrict__ offs, int* __restrict__ cur)
{
    __shared__ int sums[1024];
    int tid = threadIdx.x;
    const int CH = (NN + 1023) / 1024;  // 49
    int begin = tid * CH;
    int end = begin + CH < NN ? begin + CH : NN;
    int s = 0;
    for (int i = begin; i < end; ++i) s += cnt[i];
    sums[tid] = s;
    __syncthreads();
    for (int d = 1; d < 1024; d <<= 1) {
        int u = (tid >= d) ? sums[tid - d] : 0;
        __syncthreads();
        sums[tid] += u;
        __syncthreads();
    }
    int run = (tid == 0) ? 0 : sums[tid - 1];
    for (int i = begin; i < end; ++i) {
        offs[i] = run; cur[i] = run;
        run += cnt[i];
    }
    if (tid == 1023) offs[NN] = run;  // == NE
}

__global__ __launch_bounds__(256) void k_scatter(const int* __restrict__ dst,
                                                 int* __restrict__ cur, int* __restrict__ sorted)
{
    int e = blockIdx.x * 256 + threadIdx.x;
    if (e < NE) {
        int p = atomicAdd(&cur[dst[e]], 1);
        sorted[p] = e;
    }
}

// ---------------- generic linear: out[n][0..255] = f(h[n]) @ W + b ----------------
// f = identity (BN=false) or bn-scale/shift + relu (BN=true) applied to input reads.
// block = 256 threads (4 waves), 64 rows/block (16 rows per wave), K-tiles of 32.
template <int K, bool BN>
__global__ __launch_bounds__(256, 2) void k_linear(
    const float* __restrict__ h, const float* __restrict__ W,
    const float* __restrict__ bvec, const float* __restrict__ scale,
    const float* __restrict__ shift, float* __restrict__ out)
{
    __shared__ float Wl[32 * 256];  // 32 KB
    __shared__ float hl[64 * 32];   // 8 KB
    int tid = threadIdx.x;
    int lane = tid & 63, wave = tid >> 6;
    int row0 = blockIdx.x * 64;
    float acc[16][4];
    #pragma unroll
    for (int r = 0; r < 16; ++r)
        #pragma unroll
        for (int j = 0; j < 4; ++j) acc[r][j] = 0.f;

    for (int kt = 0; kt < K / 32; ++kt) {
        // stage W k-tile (rows kt*32 .. +32, all 256 cols), contiguous copy
        for (int i = tid * 4; i < 32 * 256; i += 1024) {
            *(float4*)(Wl + i) = *(const float4*)(W + (size_t)kt * 32 * 256 + i);
        }
        // stage 64 h rows x 32 k, with optional BN+relu transform
        for (int i = tid; i < 64 * 32; i += 256) {
            int r = i >> 5, k = i & 31;
            int row = row0 + r;
            float v = 0.f;
            if (row < NN) {
                v = h[(size_t)row * K + kt * 32 + k];
                if (BN) {
                    int gk = kt * 32 + k;
                    v = fmaxf(fmaf(v, scale[gk], shift[gk]), 0.f);
                }
            }
            hl[i] = v;
        }
        __syncthreads();
        #pragma unroll 4
        for (int k = 0; k < 32; ++k) {
            float w0 = Wl[k * 256 + lane];
            float w1 = Wl[k * 256 + 64 + lane];
            float w2 = Wl[k * 256 + 128 + lane];
            float w3 = Wl[k * 256 + 192 + lane];
            #pragma unroll
            for (int r = 0; r < 16; ++r) {
                float hb = hl[(wave * 16 + r) * 32 + k];  // LDS broadcast, conflict-free
                acc[r][0] = fmaf(hb, w0, acc[r][0]);
                acc[r][1] = fmaf(hb, w1, acc[r][1]);
                acc[r][2] = fmaf(hb, w2, acc[r][2]);
                acc[r][3] = fmaf(hb, w3, acc[r][3]);
            }
        }
        __syncthreads();
    }
    float b0 = bvec[lane], b1 = bvec[64 + lane], b2 = bvec[128 + lane], b3 = bvec[192 + lane];
    #pragma unroll
    for (int r = 0; r < 16; ++r) {
        int row = row0 + wave * 16 + r;
        if (row < NN) {
            float* o = out + (size_t)row * 256;
            o[lane]       = acc[r][0] + b0;
            o[64 + lane]  = acc[r][1] + b1;
            o[128 + lane] = acc[r][2] + b2;
            o[192 + lane] = acc[r][3] + b3;
        }
    }
}

// ---------------- edge logits: logits[e][h] = att[h] . leaky(xl[src]+xr[dst]+ea@We) ----------------
// wave per 8 edges; We kept in registers (64 VGPR/lane), no LDS.
__global__ __launch_bounds__(256) void k_edge_logits(
    const float* __restrict__ xl, const float* __restrict__ xr,
    const float* __restrict__ ea, const float* __restrict__ We,
    const float* __restrict__ att, const int* __restrict__ src,
    const int* __restrict__ dst, float* __restrict__ logits)
{
    int tid = threadIdx.x;
    int lane = tid & 63, wave = tid >> 6;
    float wreg[4][16];
    #pragma unroll
    for (int h = 0; h < 4; ++h)
        #pragma unroll
        for (int k = 0; k < 16; ++k) wreg[h][k] = We[k * 256 + h * 64 + lane];
    float areg[4];
    #pragma unroll
    for (int h = 0; h < 4; ++h) areg[h] = att[h * 64 + lane];

    int e0 = blockIdx.x * 32 + wave * 8;
    for (int t = 0; t < 8; ++t) {
        int e = e0 + t;
        if (e >= NE) return;
        int s = src[e], d = dst[e];
        const float4* eap = (const float4*)(ea + (size_t)e * 16);
        float4 A = eap[0], B = eap[1], Cv = eap[2], D = eap[3];
        float eav[16] = {A.x, A.y, A.z, A.w, B.x, B.y, B.z, B.w,
                         Cv.x, Cv.y, Cv.z, Cv.w, D.x, D.y, D.z, D.w};
        float lg[4];
        #pragma unroll
        for (int h = 0; h < 4; ++h) {
            float em = 0.f;
            #pragma unroll
            for (int k = 0; k < 16; ++k) em = fmaf(eav[k], wreg[h][k], em);
            float zv = xl[(size_t)s * 256 + h * 64 + lane] +
                       xr[(size_t)d * 256 + h * 64 + lane] + em;
            zv = (zv > 0.f) ? zv : kSlope * zv;
            lg[h] = zv * areg[h];
        }
        #pragma unroll
        for (int o = 32; o > 0; o >>= 1) {
            #pragma unroll
            for (int h = 0; h < 4; ++h) lg[h] += __shfl_xor(lg[h], o, 64);
        }
        if (lane == 0) {
            *(float4*)(logits + (size_t)e * 4) = make_float4(lg[0], lg[1], lg[2], lg[3]);
        }
    }
}

// ---------------- aggregation: wave per dst node over sorted edges ----------------
template <bool CONCAT>
__global__ __launch_bounds__(256) void k_aggregate(
    const float* __restrict__ xl, const float* __restrict__ logits,
    const int* __restrict__ src, const int* __restrict__ sorted,
    const int* __restrict__ offs, const float* __restrict__ bias,
    float* __restrict__ out)
{
    int tid = threadIdx.x;
    int lane = tid & 63, wave = tid >> 6;
    int n = blockIdx.x * 4 + wave;
    if (n >= NN) return;
    int beg = offs[n], end = offs[n + 1];

    float m0 = -INFINITY, m1 = -INFINITY, m2 = -INFINITY, m3 = -INFINITY;
    for (int i = beg + lane; i < end; i += 64) {
        float4 lg = *(const float4*)(logits + (size_t)sorted[i] * 4);
        m0 = fmaxf(m0, lg.x); m1 = fmaxf(m1, lg.y);
        m2 = fmaxf(m2, lg.z); m3 = fmaxf(m3, lg.w);
    }
    #pragma unroll
    for (int o = 32; o > 0; o >>= 1) {
        m0 = fmaxf(m0, __shfl_xor(m0, o, 64));
        m1 = fmaxf(m1, __shfl_xor(m1, o, 64));
        m2 = fmaxf(m2, __shfl_xor(m2, o, 64));
        m3 = fmaxf(m3, __shfl_xor(m3, o, 64));
    }
    float s0 = 0.f, s1 = 0.f, s2 = 0.f, s3 = 0.f;
    for (int i = beg + lane; i < end; i += 64) {
        float4 lg = *(const float4*)(logits + (size_t)sorted[i] * 4);
        s0 += __expf(lg.x - m0); s1 += __expf(lg.y - m1);
        s2 += __expf(lg.z - m2); s3 += __expf(lg.w - m3);
    }
    #pragma unroll
    for (int o = 32; o > 0; o >>= 1) {
        s0 += __shfl_xor(s0, o, 64); s1 += __shfl_xor(s1, o, 64);
        s2 += __shfl_xor(s2, o, 64); s3 += __shfl_xor(s3, o, 64);
    }
    float i0 = 1.f / (s0 + 1e-16f), i1 = 1.f / (s1 + 1e-16f);
    float i2 = 1.f / (s2 + 1e-16f), i3 = 1.f / (s3 + 1e-16f);

    float a0 = 0.f, a1 = 0.f, a2 = 0.f, a3 = 0.f;
    for (int i = beg; i < end; ++i) {
        int e = sorted[i];
        float4 lg = *(const float4*)(logits + (size_t)e * 4);
        const float* xp = xl + (size_t)src[e] * 256;
        float w0 = __expf(lg.x - m0) * i0;
        float w1 = __expf(lg.y - m1) * i1;
        float w2 = __expf(lg.z - m2) * i2;
        float w3 = __expf(lg.w - m3) * i3;
        a0 = fmaf(w0, xp[lane], a0);
        a1 = fmaf(w1, xp[64 + lane], a1);
        a2 = fmaf(w2, xp[128 + lane], a2);
        a3 = fmaf(w3, xp[192 + lane], a3);
    }
    if (CONCAT) {
        float* o = out + (size_t)n * 256;
        o[lane]       = a0 + bias[lane];
        o[64 + lane]  = a1 + bias[64 + lane];
        o[128 + lane] = a2 + bias[128 + lane];
        o[192 + lane] = a3 + bias[192 + lane];
    } else {
        out[(size_t)n * 64 + lane] = 0.25f * (a0 + a1 + a2 + a3) + bias[lane];
    }
}

// ---------------- batchnorm stats (sum, sumsq per channel) ----------------
template <int CH>
__global__ __launch_bounds__(256) void k_bn_stats(const float* __restrict__ h,
                                                  float* __restrict__ sum,
                                                  float* __restrict__ sumsq)
{
    constexpr int RP = 256 / CH;
    int tid = threadIdx.x;
    int c = tid % CH;
    int rsub = tid / CH;
    float s = 0.f, q = 0.f;
    for (int n = blockIdx.x * RP + rsub; n < NN; n += gridDim.x * RP) {
        float v = h[(size_t)n * CH + c];
        s += v; q = fmaf(v, v, q);
    }
    __shared__ float ls[256], lq[256];
    ls[tid] = s; lq[tid] = q;
    __syncthreads();
    if (tid < CH) {
        #pragma unroll
        for (int r = 1; r < RP; ++r) { s += ls[tid + r * CH]; q += lq[tid + r * CH]; }
        atomicAdd(&sum[tid], s);
        atomicAdd(&sumsq[tid], q);
    }
}

__global__ void k_bn_finalize(const float* __restrict__ sum, const float* __restrict__ sumsq,
                              const float* __restrict__ g, const float* __restrict__ beta,
                              float* __restrict__ scale, float* __restrict__ shift, int CH)
{
    int c = threadIdx.x;
    if (c >= CH) return;
    float inv_n = 1.f / (float)NN;
    float mu = sum[c] * inv_n;
    float var = sumsq[c] * inv_n - mu * mu;
    float sc = g[c] / sqrtf(var + kBnEps);
    scale[c] = sc;
    shift[c] = fmaf(-mu, sc, beta[c]);
}

// ---------------- graph mean-pool (batch is sorted) ----------------
__global__ __launch_bounds__(64) void k_pool(const float* __restrict__ h2,
                                             const float* __restrict__ scale,
                                             const float* __restrict__ shift,
                                             const int* __restrict__ batch,
                                             float* __restrict__ pooled)
{
    int lane = threadIdx.x;
    int start = blockIdx.x * 128;
    int stop = start + 128 < NN ? start + 128 : NN;
    if (start >= NN) return;
    float sc = scale[lane], sh = shift[lane];
    int curg = batch[start];
    float acc = 0.f;
    for (int n = start; n < stop; ++n) {
        int g = batch[n];
        if (g != curg) {
            atomicAdd(&pooled[(size_t)curg * 64 + lane], acc);
            acc = 0.f; curg = g;
        }
        acc += fmaf(h2[(size_t)n * 64 + lane], sc, sh);
    }
    atomicAdd(&pooled[(size_t)curg * 64 + lane], acc);
}

__global__ __launch_bounds__(256) void k_gcnt(const int* __restrict__ batch, int* __restrict__ gcnt)
{
    int n = blockIdx.x * 256 + threadIdx.x;
    if (n < NN) atomicAdd(&gcnt[batch[n]], 1);
}

// ---------------- MLP head: 64 -> 32 -> 16 -> 1 per graph ----------------
__global__ __launch_bounds__(64) void k_mlp(const float* __restrict__ pooled,
                                            const int* __restrict__ gcnt,
                                            const float* __restrict__ Wm1, const float* __restrict__ bm1,
                                            const float* __restrict__ Wm2, const float* __restrict__ bm2,
                                            const float* __restrict__ Wm3, const float* __restrict__ bm3,
                                            float* __restrict__ out)
{
    int g = blockIdx.x, lane = threadIdx.x;
    __shared__ float p[64], z1[32], z2[16];
    float cntf = fmaxf((float)gcnt[g], 1.f);
    p[lane] = pooled[(size_t)g * 64 + lane] / cntf;
    __syncthreads();
    if (lane < 32) {
        float a = bm1[lane];
        #pragma unroll
        for (int k = 0; k < 64; ++k) a = fmaf(p[k], Wm1[k * 32 + lane], a);
        z1[lane] = fmaxf(a, 0.f);
    }
    __syncthreads();
    if (lane < 16) {
        float a = bm2[lane];
        #pragma unroll
        for (int k = 0; k < 32; ++k) a = fmaf(z1[k], Wm2[k * 16 + lane], a);
        z2[lane] = fmaxf(a, 0.f);
    }
    __syncthreads();
    if (lane == 0) {
        float a = bm3[0];
        #pragma unroll
        for (int k = 0; k < 16; ++k) a = fmaf(z2[k], Wm3[k], a);
        out[g] = a;
    }
}

// ---------------- host launcher ----------------
extern "C" void kernel_launch(void* const* d_in, const int* in_sizes, int n_in,
                              void* d_out, int out_size, void* d_ws, size_t ws_size,
                              hipStream_t stream)
{
    const float* x     = (const float*)d_in[0];
    const float* ea    = (const float*)d_in[1];
    const int*   ei    = (const int*)d_in[2];
    const int*   bat   = (const int*)d_in[3];
    const float* W_in  = (const float*)d_in[4];
    const float* b_in  = (const float*)d_in[5];
    const float* Wl0   = (const float*)d_in[6];
    const float* bl0   = (const float*)d_in[7];
    const float* Wr0   = (const float*)d_in[8];
    const float* br0   = (const float*)d_in[9];
    const float* We0   = (const float*)d_in[10];
    const float* att0  = (const float*)d_in[11];
    const float* bias0 = (const float*)d_in[12];
    const float* g0    = (const float*)d_in[13];
    const float* beta0 = (const float*)d_in[14];
    const float* Wl1   = (const float*)d_in[15];
    const float* bl1   = (const float*)d_in[16];
    const float* Wr1   = (const float*)d_in[17];
    const float* br1   = (const float*)d_in[18];
    const float* We1   = (const float*)d_in[19];
    const float* att1  = (const float*)d_in[20];
    const float* bias1 = (const float*)d_in[21];
    const float* g1    = (const float*)d_in[22];
    const float* beta1 = (const float*)d_in[23];
    const float* Wm1   = (const float*)d_in[24];
    const float* bm1   = (const float*)d_in[25];
    const float* Wm2   = (const float*)d_in[26];
    const float* bm2   = (const float*)d_in[27];
    const float* Wm3   = (const float*)d_in[28];
    const float* bm3   = (const float*)d_in[29];
    const int* src = ei;
    const int* dst = ei + NE;
    float* out = (float*)d_out;

    char* p = (char*)d_ws;
    auto take = [&](size_t nbytes) -> char* {
        char* q = p;
        p += (nbytes + 255) & ~(size_t)255;
        return q;
    };
    // ---- zero zone (one memset) ----
    char* z0 = p;
    int*   hist   = (int*)take((size_t)NN * 4);
    float* bns0   = (float*)take(256 * 4);
    float* bnq0   = (float*)take(256 * 4);
    float* bns1   = (float*)take(64 * 4);
    float* bnq1   = (float*)take(64 * 4);
    float* pooled = (float*)take((size_t)NG * 64 * 4);
    int*   gcnt   = (int*)take((size_t)NG * 4);
    size_t zbytes = (size_t)(p - z0);
    // ---- rest of workspace ----
    int*   offs   = (int*)take((size_t)(NN + 1) * 4);
    int*   curs   = (int*)take((size_t)NN * 4);
    int*   sorted = (int*)take((size_t)NE * 4);
    float* logits = (float*)take((size_t)NE * 4 * 4);
    float* h0     = (float*)take((size_t)NN * 64 * 4);    // reused as h2
    float* xl     = (float*)take((size_t)NN * 256 * 4);
    float* xr     = (float*)take((size_t)NN * 256 * 4);
    float* h1     = (float*)take((size_t)NN * 256 * 4);
    float* scale0 = (float*)take(256 * 4);
    float* shift0 = (float*)take(256 * 4);
    float* scale1 = (float*)take(64 * 4);
    float* shift1 = (float*)take(64 * 4);

    hipMemsetAsync(z0, 0, zbytes, stream);

    k_input_proj<<<(NN + 3) / 4, 256, 0, stream>>>(x, W_in, b_in, h0);

    k_hist<<<(NE + 255) / 256, 256, 0, stream>>>(dst, hist);
    k_scan<<<1, 1024, 0, stream>>>(hist, offs, curs);
    k_scatter<<<(NE + 255) / 256, 256, 0, stream>>>(dst, curs, sorted);

    // ---- GATv2 layer 0 ----
    k_linear<64, false><<<(NN + 63) / 64, 256, 0, stream>>>(h0, Wl0, bl0, nullptr, nullptr, xl);
    k_linear<64, false><<<(NN + 63) / 64, 256, 0, stream>>>(h0, Wr0, br0, nullptr, nullptr, xr);
    k_edge_logits<<<(NE + 31) / 32, 256, 0, stream>>>(xl, xr, ea, We0, att0, src, dst, logits);
    k_aggregate<true><<<(NN + 3) / 4, 256, 0, stream>>>(xl, logits, src, sorted, offs, bias0, h1);
    k_bn_stats<256><<<128, 256, 0, stream>>>(h1, bns0, bnq0);
    k_bn_finalize<<<1, 256, 0, stream>>>(bns0, bnq0, g0, beta0, scale0, shift0, 256);

    // ---- GATv2 layer 1 (BN0+relu folded into input reads) ----
    k_linear<256, true><<<(NN + 63) / 64, 256, 0, stream>>>(h1, Wl1, bl1, scale0, shift0, xl);
    k_linear<256, true><<<(NN + 63) / 64, 256, 0, stream>>>(h1, Wr1, br1, scale0, shift0, xr);
    k_edge_logits<<<(NE + 31) / 32, 256, 0, stream>>>(xl, xr, ea, We1, att1, src, dst, logits);
    k_aggregate<false><<<(NN + 3) / 4, 256, 0, stream>>>(xl, logits, src, sorted, offs, bias1, h0);
    k_bn_stats<64><<<128, 256, 0, stream>>>(h0, bns1, bnq1);
    k_bn_finalize<<<1, 64, 0, stream>>>(bns1, bnq1, g1, beta1, scale1, shift1, 64);

    // ---- pool + MLP ----
    k_pool<<<(NN + 127) / 128, 64, 0, stream>>>(h0, scale1, shift1, bat, pooled);
    k_gcnt<<<(NN + 255) / 256, 256, 0, stream>>>(bat, gcnt);
    k_mlp<<<NG, 64, 0, stream>>>(pooled, gcnt, Wm1, bm1, Wm2, bm2, Wm3, bm3, out);
}

// Round 2
// 1611.368 us; speedup vs baseline: 1.0638x; 1.0638x over previous
//
#include <hip/hip_runtime.h>
#include <math.h>

constexpr int NN = 50000;
constexpr int NE = 600000;
constexpr int NG = 256;
constexpr float kBnEps = 1e-5f;
constexpr float kSlope = 0.2f;

// ---------------- input projection: h0 = relu(x @ W_in + b_in) ----------------
__global__ __launch_bounds__(256) void k_input_proj(
    const float* __restrict__ x, const float* __restrict__ W,
    const float* __restrict__ b, float* __restrict__ h0)
{
    __shared__ float Wl[64 * 64];
    __shared__ float bl[64];
    int tid = threadIdx.x;
    for (int i = tid; i < 64 * 64; i += 256) Wl[i] = W[i];
    if (tid < 64) bl[tid] = b[tid];
    __syncthreads();
    int lane = tid & 63, wave = tid >> 6;
    int row = blockIdx.x * 4 + wave;
    if (row >= NN) return;
    float xv = x[(size_t)row * 64 + lane];
    float acc = bl[lane];
    #pragma unroll
    for (int k = 0; k < 64; ++k) {
        float hb = __shfl(xv, k, 64);
        acc = fmaf(hb, Wl[k * 64 + lane], acc);
    }
    h0[(size_t)row * 64 + lane] = fmaxf(acc, 0.f);
}

// ---------------- counting sort of edges by dst ----------------
__global__ __launch_bounds__(256) void k_hist(const int* __restrict__ dst, int* __restrict__ cnt)
{
    int e = blockIdx.x * 256 + threadIdx.x;
    if (e < NE) atomicAdd(&cnt[dst[e]], 1);
}

__global__ __launch_bounds__(1024) void k_scan(const int* __restrict__ cnt,
                                               int* __restrict__ offs, int* __restrict__ cur)
{
    __shared__ int sums[1024];
    int tid = threadIdx.x;
    const int CH = (NN + 1023) / 1024;  // 49
    int begin = tid * CH;
    int end = begin + CH < NN ? begin + CH : NN;
    int s = 0;
    for (int i = begin; i < end; ++i) s += cnt[i];
    sums[tid] = s;
    __syncthreads();
    for (int d = 1; d < 1024; d <<= 1) {
        int u = (tid >= d) ? sums[tid - d] : 0;
        __syncthreads();
        sums[tid] += u;
        __syncthreads();
    }
    int run = (tid == 0) ? 0 : sums[tid - 1];
    for (int i = begin; i < end; ++i) {
        offs[i] = run; cur[i] = run;
        run += cnt[i];
    }
    if (tid == 1023) offs[NN] = run;  // == NE
}

__global__ __launch_bounds__(256) void k_scatter(const int* __restrict__ dst,
                                                 const int* __restrict__ src,
                                                 int* __restrict__ cur,
                                                 int* __restrict__ sorted,
                                                 int* __restrict__ srcs)
{
    int e = blockIdx.x * 256 + threadIdx.x;
    if (e < NE) {
        int p = atomicAdd(&cur[dst[e]], 1);
        sorted[p] = e;
        srcs[p] = src[e];
    }
}

// ---------------- generic linear: out[n][0..255] = f(h[n]) @ W + b ----------------
template <int K, bool BN>
__global__ __launch_bounds__(256, 2) void k_linear(
    const float* __restrict__ h, const float* __restrict__ W,
    const float* __restrict__ bvec, const float* __restrict__ scale,
    const float* __restrict__ shift, float* __restrict__ out)
{
    __shared__ float Wl[32 * 256];  // 32 KB
    __shared__ float hl[64 * 32];   // 8 KB
    int tid = threadIdx.x;
    int lane = tid & 63, wave = tid >> 6;
    int row0 = blockIdx.x * 64;
    float acc[16][4];
    #pragma unroll
    for (int r = 0; r < 16; ++r)
        #pragma unroll
        for (int j = 0; j < 4; ++j) acc[r][j] = 0.f;

    for (int kt = 0; kt < K / 32; ++kt) {
        for (int i = tid * 4; i < 32 * 256; i += 1024) {
            *(float4*)(Wl + i) = *(const float4*)(W + (size_t)kt * 32 * 256 + i);
        }
        for (int i = tid; i < 64 * 32; i += 256) {
            int r = i >> 5, k = i & 31;
            int row = row0 + r;
            float v = 0.f;
            if (row < NN) {
                v = h[(size_t)row * K + kt * 32 + k];
                if (BN) {
                    int gk = kt * 32 + k;
                    v = fmaxf(fmaf(v, scale[gk], shift[gk]), 0.f);
                }
            }
            hl[i] = v;
        }
        __syncthreads();
        #pragma unroll 4
        for (int k = 0; k < 32; ++k) {
            float w0 = Wl[k * 256 + lane];
            float w1 = Wl[k * 256 + 64 + lane];
            float w2 = Wl[k * 256 + 128 + lane];
            float w3 = Wl[k * 256 + 192 + lane];
            #pragma unroll
            for (int r = 0; r < 16; ++r) {
                float hb = hl[(wave * 16 + r) * 32 + k];
                acc[r][0] = fmaf(hb, w0, acc[r][0]);
                acc[r][1] = fmaf(hb, w1, acc[r][1]);
                acc[r][2] = fmaf(hb, w2, acc[r][2]);
                acc[r][3] = fmaf(hb, w3, acc[r][3]);
            }
        }
        __syncthreads();
    }
    float b0 = bvec[lane], b1 = bvec[64 + lane], b2 = bvec[128 + lane], b3 = bvec[192 + lane];
    #pragma unroll
    for (int r = 0; r < 16; ++r) {
        int row = row0 + wave * 16 + r;
        if (row < NN) {
            float* o = out + (size_t)row * 256;
            o[lane]       = acc[r][0] + b0;
            o[64 + lane]  = acc[r][1] + b1;
            o[128 + lane] = acc[r][2] + b2;
            o[192 + lane] = acc[r][3] + b3;
        }
    }
}

// ---------------- fused attention: wave per dst node, online per-head softmax --------
// Lane layout: lane holds channels [4*lane .. 4*lane+3]; head = lane/16.
// Per edge (dst-sorted): gather xl[src] (float4/lane), ea broadcast, em on the fly,
// logit reduced over the 16-lane head group, online-softmax accumulate of xl message.
template <bool CONCAT>
__global__ __launch_bounds__(256) void k_attn(
    const float* __restrict__ xl, const float* __restrict__ xr,
    const float* __restrict__ ea, const float* __restrict__ We,
    const float* __restrict__ att, const int* __restrict__ sorted,
    const int* __restrict__ srcs, const int* __restrict__ offs,
    const float* __restrict__ bias, float* __restrict__ out)
{
    int tid = threadIdx.x;
    int lane = tid & 63, wave = tid >> 6;
    // We fragment: wr[k] = We[k*256 + 4*lane .. +3]
    float4 wr[16];
    #pragma unroll
    for (int k = 0; k < 16; ++k) wr[k] = ((const float4*)(We + k * 256))[lane];
    float4 ar = ((const float4*)att)[lane];  // att for this lane's 4 channels

    int n = blockIdx.x * 4 + wave;
    if (n >= NN) return;
    int beg = offs[n], end = offs[n + 1];

    float4 xr4 = ((const float4*)(xr + (size_t)n * 256))[lane];

    float m = -INFINITY, ssum = 0.f;
    float a0 = 0.f, a1 = 0.f, a2 = 0.f, a3 = 0.f;

    float4 xv, eA, eB, eC, eD;
    if (beg < end) {
        int e = sorted[beg], s = srcs[beg];
        xv = ((const float4*)(xl + (size_t)s * 256))[lane];
        const float4* eap = (const float4*)(ea + (size_t)e * 16);
        eA = eap[0]; eB = eap[1]; eC = eap[2]; eD = eap[3];
    }
    for (int i = beg; i < end; ++i) {
        float4 cx = xv;
        float eav[16] = {eA.x, eA.y, eA.z, eA.w, eB.x, eB.y, eB.z, eB.w,
                         eC.x, eC.y, eC.z, eC.w, eD.x, eD.y, eD.z, eD.w};
        if (i + 1 < end) {  // prefetch next edge
            int e2 = sorted[i + 1], s2 = srcs[i + 1];
            xv = ((const float4*)(xl + (size_t)s2 * 256))[lane];
            const float4* eap = (const float4*)(ea + (size_t)e2 * 16);
            eA = eap[0]; eB = eap[1]; eC = eap[2]; eD = eap[3];
        }
        float em0 = 0.f, em1 = 0.f, em2 = 0.f, em3 = 0.f;
        #pragma unroll
        for (int k = 0; k < 16; ++k) {
            em0 = fmaf(eav[k], wr[k].x, em0);
            em1 = fmaf(eav[k], wr[k].y, em1);
            em2 = fmaf(eav[k], wr[k].z, em2);
            em3 = fmaf(eav[k], wr[k].w, em3);
        }
        float z0 = cx.x + xr4.x + em0;
        float z1 = cx.y + xr4.y + em1;
        float z2 = cx.z + xr4.z + em2;
        float z3 = cx.w + xr4.w + em3;
        z0 = (z0 > 0.f) ? z0 : kSlope * z0;
        z1 = (z1 > 0.f) ? z1 : kSlope * z1;
        z2 = (z2 > 0.f) ? z2 : kSlope * z2;
        z3 = (z3 > 0.f) ? z3 : kSlope * z3;
        float p = fmaf(z0, ar.x, fmaf(z1, ar.y, fmaf(z2, ar.z, z3 * ar.w)));
        // reduce over 16-lane head group
        p += __shfl_xor(p, 1, 64);
        p += __shfl_xor(p, 2, 64);
        p += __shfl_xor(p, 4, 64);
        p += __shfl_xor(p, 8, 64);
        // online softmax update (per-head; lanes in a group are redundant but consistent)
        float mn = fmaxf(m, p);
        float sc = __expf(m - mn);
        float w = __expf(p - mn);
        ssum = fmaf(ssum, sc, w);
        a0 = fmaf(a0, sc, w * cx.x);
        a1 = fmaf(a1, sc, w * cx.y);
        a2 = fmaf(a2, sc, w * cx.z);
        a3 = fmaf(a3, sc, w * cx.w);
        m = mn;
    }
    float inv = 1.f / (ssum + 1e-16f);
    if (CONCAT) {
        float4 b4 = ((const float4*)bias)[lane];
        float4 o;
        o.x = fmaf(a0, inv, b4.x);
        o.y = fmaf(a1, inv, b4.y);
        o.z = fmaf(a2, inv, b4.z);
        o.w = fmaf(a3, inv, b4.w);
        ((float4*)(out + (size_t)n * 256))[lane] = o;
    } else {
        float v0 = a0 * inv, v1 = a1 * inv, v2 = a2 * inv, v3 = a3 * inv;
        v0 += __shfl_xor(v0, 16, 64); v0 += __shfl_xor(v0, 32, 64);
        v1 += __shfl_xor(v1, 16, 64); v1 += __shfl_xor(v1, 32, 64);
        v2 += __shfl_xor(v2, 16, 64); v2 += __shfl_xor(v2, 32, 64);
        v3 += __shfl_xor(v3, 16, 64); v3 += __shfl_xor(v3, 32, 64);
        if (lane < 16) {
            float4 b4 = ((const float4*)bias)[lane];
            float4 o;
            o.x = fmaf(0.25f, v0, b4.x);
            o.y = fmaf(0.25f, v1, b4.y);
            o.z = fmaf(0.25f, v2, b4.z);
            o.w = fmaf(0.25f, v3, b4.w);
            ((float4*)(out + (size_t)n * 64))[lane] = o;
        }
    }
}

// ---------------- batchnorm stats (sum, sumsq per channel) ----------------
template <int CH>
__global__ __launch_bounds__(256) void k_bn_stats(const float* __restrict__ h,
                                                  float* __restrict__ sum,
                                                  float* __restrict__ sumsq)
{
    constexpr int RP = 256 / CH;
    int tid = threadIdx.x;
    int c = tid % CH;
    int rsub = tid / CH;
    float s = 0.f, q = 0.f;
    for (int n = blockIdx.x * RP + rsub; n < NN; n += gridDim.x * RP) {
        float v = h[(size_t)n * CH + c];
        s += v; q = fmaf(v, v, q);
    }
    __shared__ float ls[256], lq[256];
    ls[tid] = s; lq[tid] = q;
    __syncthreads();
    if (tid < CH) {
        #pragma unroll
        for (int r = 1; r < RP; ++r) { s += ls[tid + r * CH]; q += lq[tid + r * CH]; }
        atomicAdd(&sum[tid], s);
        atomicAdd(&sumsq[tid], q);
    }
}

__global__ void k_bn_finalize(const float* __restrict__ sum, const float* __restrict__ sumsq,
                              const float* __restrict__ g, const float* __restrict__ beta,
                              float* __restrict__ scale, float* __restrict__ shift, int CH)
{
    int c = threadIdx.x;
    if (c >= CH) return;
    float inv_n = 1.f / (float)NN;
    float mu = sum[c] * inv_n;
    float var = sumsq[c] * inv_n - mu * mu;
    float sc = g[c] / sqrtf(var + kBnEps);
    scale[c] = sc;
    shift[c] = fmaf(-mu, sc, beta[c]);
}

// ---------------- graph mean-pool (batch is sorted) ----------------
__global__ __launch_bounds__(64) void k_pool(const float* __restrict__ h2,
                                             const float* __restrict__ scale,
                                             const float* __restrict__ shift,
                                             const int* __restrict__ batch,
                                             float* __restrict__ pooled)
{
    int lane = threadIdx.x;
    int start = blockIdx.x * 128;
    int stop = start + 128 < NN ? start + 128 : NN;
    if (start >= NN) return;
    float sc = scale[lane], sh = shift[lane];
    int curg = batch[start];
    float acc = 0.f;
    for (int n = start; n < stop; ++n) {
        int g = batch[n];
        if (g != curg) {
            atomicAdd(&pooled[(size_t)curg * 64 + lane], acc);
            acc = 0.f; curg = g;
        }
        acc += fmaf(h2[(size_t)n * 64 + lane], sc, sh);
    }
    atomicAdd(&pooled[(size_t)curg * 64 + lane], acc);
}

__global__ __launch_bounds__(256) void k_gcnt(const int* __restrict__ batch, int* __restrict__ gcnt)
{
    int n = blockIdx.x * 256 + threadIdx.x;
    if (n < NN) atomicAdd(&gcnt[batch[n]], 1);
}

// ---------------- MLP head: 64 -> 32 -> 16 -> 1 per graph ----------------
__global__ __launch_bounds__(64) void k_mlp(const float* __restrict__ pooled,
                                            const int* __restrict__ gcnt,
                                            const float* __restrict__ Wm1, const float* __restrict__ bm1,
                                            const float* __restrict__ Wm2, const float* __restrict__ bm2,
                                            const float* __restrict__ Wm3, const float* __restrict__ bm3,
                                            float* __restrict__ out)
{
    int g = blockIdx.x, lane = threadIdx.x;
    __shared__ float p[64], z1[32], z2[16];
    float cntf = fmaxf((float)gcnt[g], 1.f);
    p[lane] = pooled[(size_t)g * 64 + lane] / cntf;
    __syncthreads();
    if (lane < 32) {
        float a = bm1[lane];
        #pragma unroll
        for (int k = 0; k < 64; ++k) a = fmaf(p[k], Wm1[k * 32 + lane], a);
        z1[lane] = fmaxf(a, 0.f);
    }
    __syncthreads();
    if (lane < 16) {
        float a = bm2[lane];
        #pragma unroll
        for (int k = 0; k < 32; ++k) a = fmaf(z1[k], Wm2[k * 16 + lane], a);
        z2[lane] = fmaxf(a, 0.f);
    }
    __syncthreads();
    if (lane == 0) {
        float a = bm3[0];
        #pragma unroll
        for (int k = 0; k < 16; ++k) a = fmaf(z2[k], Wm3[k], a);
        out[g] = a;
    }
}

// ---------------- host launcher ----------------
extern "C" void kernel_launch(void* const* d_in, const int* in_sizes, int n_in,
                              void* d_out, int out_size, void* d_ws, size_t ws_size,
                              hipStream_t stream)
{
    const float* x     = (const float*)d_in[0];
    const float* ea    = (const float*)d_in[1];
    const int*   ei    = (const int*)d_in[2];
    const int*   bat   = (const int*)d_in[3];
    const float* W_in  = (const float*)d_in[4];
    const float* b_in  = (const float*)d_in[5];
    const float* Wl0   = (const float*)d_in[6];
    const float* bl0   = (const float*)d_in[7];
    const float* Wr0   = (const float*)d_in[8];
    const float* br0   = (const float*)d_in[9];
    const float* We0   = (const float*)d_in[10];
    const float* att0  = (const float*)d_in[11];
    const float* bias0 = (const float*)d_in[12];
    const float* g0    = (const float*)d_in[13];
    const float* beta0 = (const float*)d_in[14];
    const float* Wl1   = (const float*)d_in[15];
    const float* bl1   = (const float*)d_in[16];
    const float* Wr1   = (const float*)d_in[17];
    const float* br1   = (const float*)d_in[18];
    const float* We1   = (const float*)d_in[19];
    const float* att1  = (const float*)d_in[20];
    const float* bias1 = (const float*)d_in[21];
    const float* g1    = (const float*)d_in[22];
    const float* beta1 = (const float*)d_in[23];
    const float* Wm1   = (const float*)d_in[24];
    const float* bm1   = (const float*)d_in[25];
    const float* Wm2   = (const float*)d_in[26];
    const float* bm2   = (const float*)d_in[27];
    const float* Wm3   = (const float*)d_in[28];
    const float* bm3   = (const float*)d_in[29];
    const int* src = ei;
    const int* dst = ei + NE;
    float* out = (float*)d_out;

    char* p = (char*)d_ws;
    auto take = [&](size_t nbytes) -> char* {
        char* q = p;
        p += (nbytes + 255) & ~(size_t)255;
        return q;
    };
    // ---- zero zone (one memset) ----
    char* z0 = p;
    int*   hist   = (int*)take((size_t)NN * 4);
    float* bns0   = (float*)take(256 * 4);
    float* bnq0   = (float*)take(256 * 4);
    float* bns1   = (float*)take(64 * 4);
    float* bnq1   = (float*)take(64 * 4);
    float* pooled = (float*)take((size_t)NG * 64 * 4);
    int*   gcnt   = (int*)take((size_t)NG * 4);
    size_t zbytes = (size_t)(p - z0);
    // ---- rest of workspace ----
    int*   offs   = (int*)take((size_t)(NN + 1) * 4);
    int*   curs   = (int*)take((size_t)NN * 4);
    int*   sorted = (int*)take((size_t)NE * 4);
    int*   srcs   = (int*)take((size_t)NE * 4);
    float* h0     = (float*)take((size_t)NN * 64 * 4);    // reused as h2
    float* xl     = (float*)take((size_t)NN * 256 * 4);
    float* xr     = (float*)take((size_t)NN * 256 * 4);
    float* h1     = (float*)take((size_t)NN * 256 * 4);
    float* scale0 = (float*)take(256 * 4);
    float* shift0 = (float*)take(256 * 4);
    float* scale1 = (float*)take(64 * 4);
    float* shift1 = (float*)take(64 * 4);

    hipMemsetAsync(z0, 0, zbytes, stream);

    k_input_proj<<<(NN + 3) / 4, 256, 0, stream>>>(x, W_in, b_in, h0);

    k_hist<<<(NE + 255) / 256, 256, 0, stream>>>(dst, hist);
    k_scan<<<1, 1024, 0, stream>>>(hist, offs, curs);
    k_scatter<<<(NE + 255) / 256, 256, 0, stream>>>(dst, src, curs, sorted, srcs);

    // ---- GATv2 layer 0 ----
    k_linear<64, false><<<(NN + 63) / 64, 256, 0, stream>>>(h0, Wl0, bl0, nullptr, nullptr, xl);
    k_linear<64, false><<<(NN + 63) / 64, 256, 0, stream>>>(h0, Wr0, br0, nullptr, nullptr, xr);
    k_attn<true><<<(NN + 3) / 4, 256, 0, stream>>>(xl, xr, ea, We0, att0, sorted, srcs, offs, bias0, h1);
    k_bn_stats<256><<<128, 256, 0, stream>>>(h1, bns0, bnq0);
    k_bn_finalize<<<1, 256, 0, stream>>>(bns0, bnq0, g0, beta0, scale0, shift0, 256);

    // ---- GATv2 layer 1 (BN0+relu folded into linear input reads) ----
    k_linear<256, true><<<(NN + 63) / 64, 256, 0, stream>>>(h1, Wl1, bl1, scale0, shift0, xl);
    k_linear<256, true><<<(NN + 63) / 64, 256, 0, stream>>>(h1, Wr1, br1, scale0, shift0, xr);
    k_attn<false><<<(NN + 3) / 4, 256, 0, stream>>>(xl, xr, ea, We1, att1, sorted, srcs, offs, bias1, h0);
    k_bn_stats<64><<<128, 256, 0, stream>>>(h0, bns1, bnq1);
    k_bn_finalize<<<1, 64, 0, stream>>>(bns1, bnq1, g1, beta1, scale1, shift1, 64);

    // ---- pool + MLP ----
    k_pool<<<(NN + 127) / 128, 64, 0, stream>>>(h0, scale1, shift1, bat, pooled);
    k_gcnt<<<(NN + 255) / 256, 256, 0, stream>>>(bat, gcnt);
    k_mlp<<<NG, 64, 0, stream>>>(pooled, gcnt, Wm1, bm1, Wm2, bm2, Wm3, bm3, out);
}

// Round 3
// 1266.308 us; speedup vs baseline: 1.3536x; 1.2725x over previous
//
#include <hip/hip_runtime.h>
#include <math.h>

constexpr int NN = 50000;
constexpr int NE = 600000;
constexpr int NG = 256;
constexpr float kBnEps = 1e-5f;
constexpr float kSlope = 0.2f;

__device__ __forceinline__ float rdlane(float v, int l) {
    return __builtin_bit_cast(float, __builtin_amdgcn_readlane(__builtin_bit_cast(int, v), l));
}

// ---------------- input projection: h0 = relu(x @ W_in + b_in) ----------------
__global__ __launch_bounds__(256) void k_input_proj(
    const float* __restrict__ x, const float* __restrict__ W,
    const float* __restrict__ b, float* __restrict__ h0)
{
    __shared__ float Wl[64 * 64];
    __shared__ float bl[64];
    int tid = threadIdx.x;
    for (int i = tid; i < 64 * 64; i += 256) Wl[i] = W[i];
    if (tid < 64) bl[tid] = b[tid];
    __syncthreads();
    int lane = tid & 63, wave = tid >> 6;
    int row = blockIdx.x * 4 + wave;
    if (row >= NN) return;
    float xv = x[(size_t)row * 64 + lane];
    float acc = bl[lane];
    #pragma unroll
    for (int k = 0; k < 64; ++k) {
        float hb = rdlane(xv, k);
        acc = fmaf(hb, Wl[k * 64 + lane], acc);
    }
    h0[(size_t)row * 64 + lane] = fmaxf(acc, 0.f);
}

// ---------------- counting sort of edges by dst ----------------
__global__ __launch_bounds__(256) void k_hist(const int* __restrict__ dst, int* __restrict__ cnt)
{
    int e = blockIdx.x * 256 + threadIdx.x;
    if (e < NE) atomicAdd(&cnt[dst[e]], 1);
}

__global__ __launch_bounds__(1024) void k_scan(const int* __restrict__ cnt,
                                               int* __restrict__ offs, int* __restrict__ cur)
{
    __shared__ int sums[1024];
    int tid = threadIdx.x;
    const int CH = (NN + 1023) / 1024;  // 49
    int begin = tid * CH;
    int end = begin + CH < NN ? begin + CH : NN;
    int s = 0;
    for (int i = begin; i < end; ++i) s += cnt[i];
    sums[tid] = s;
    __syncthreads();
    for (int d = 1; d < 1024; d <<= 1) {
        int u = (tid >= d) ? sums[tid - d] : 0;
        __syncthreads();
        sums[tid] += u;
        __syncthreads();
    }
    int run = (tid == 0) ? 0 : sums[tid - 1];
    for (int i = begin; i < end; ++i) {
        offs[i] = run; cur[i] = run;
        run += cnt[i];
    }
    if (tid == 1023) offs[NN] = run;  // == NE
}

__global__ __launch_bounds__(256) void k_scatter(const int* __restrict__ dst,
                                                 const int* __restrict__ src,
                                                 int* __restrict__ cur,
                                                 int* __restrict__ sorted,
                                                 int* __restrict__ srcs)
{
    int e = blockIdx.x * 256 + threadIdx.x;
    if (e < NE) {
        int p = atomicAdd(&cur[dst[e]], 1);
        sorted[p] = e;
        srcs[p] = src[e];
    }
}

// ---------------- generic linear: out[n][0..255] = f(h[n]) @ W + b ----------------
// 64 rows/block (16/wave). h in registers: half-wave holds k=0..31 of one row;
// hreg[r] covers rows row0+2r (+half). Broadcast via v_readlane (off the LDS pipe).
// W k-tile (32x256 = 32 KB LDS), one ds_read_b128 per k per lane (lane = 4 cols).
template <int K, bool BN>
__global__ __launch_bounds__(256) void k_linear(
    const float* __restrict__ h, const float* __restrict__ W,
    const float* __restrict__ bvec, const float* __restrict__ scale,
    const float* __restrict__ shift, float* __restrict__ out)
{
    __shared__ float Wl[32 * 256];  // 32 KB
    int tid = threadIdx.x;
    int lane = tid & 63, wave = tid >> 6;
    int row0 = blockIdx.x * 64 + wave * 16;
    int half = lane >> 5;
    int kl = lane & 31;
    float4 acc[16];
    #pragma unroll
    for (int r = 0; r < 16; ++r) acc[r] = make_float4(0.f, 0.f, 0.f, 0.f);

    for (int kt = 0; kt < K / 32; ++kt) {
        __syncthreads();
        for (int i = tid * 4; i < 32 * 256; i += 1024) {
            *(float4*)(Wl + i) = *(const float4*)(W + (size_t)kt * 32 * 256 + i);
        }
        float hreg[8];
        float sc = 1.f, sh = 0.f;
        if (BN) { sc = scale[kt * 32 + kl]; sh = shift[kt * 32 + kl]; }
        #pragma unroll
        for (int r = 0; r < 8; ++r) {
            int row = row0 + 2 * r + half;
            if (row >= NN) row = NN - 1;
            float v = h[(size_t)row * K + kt * 32 + kl];
            if (BN) v = fmaxf(fmaf(v, sc, sh), 0.f);
            hreg[r] = v;
        }
        __syncthreads();
        #pragma unroll 8
        for (int k = 0; k < 32; ++k) {
            float4 w4 = *(const float4*)&Wl[k * 256 + 4 * lane];
            #pragma unroll
            for (int r = 0; r < 8; ++r) {
                float h0 = rdlane(hreg[r], k);
                float h1 = rdlane(hreg[r], 32 + k);
                acc[2 * r].x = fmaf(h0, w4.x, acc[2 * r].x);
                acc[2 * r].y = fmaf(h0, w4.y, acc[2 * r].y);
                acc[2 * r].z = fmaf(h0, w4.z, acc[2 * r].z);
                acc[2 * r].w = fmaf(h0, w4.w, acc[2 * r].w);
                acc[2 * r + 1].x = fmaf(h1, w4.x, acc[2 * r + 1].x);
                acc[2 * r + 1].y = fmaf(h1, w4.y, acc[2 * r + 1].y);
                acc[2 * r + 1].z = fmaf(h1, w4.z, acc[2 * r + 1].z);
                acc[2 * r + 1].w = fmaf(h1, w4.w, acc[2 * r + 1].w);
            }
        }
    }
    float4 b4 = ((const float4*)bvec)[lane];
    #pragma unroll
    for (int r = 0; r < 16; ++r) {
        int row = row0 + r;
        if (row < NN) {
            float4 o;
            o.x = acc[r].x + b4.x; o.y = acc[r].y + b4.y;
            o.z = acc[r].z + b4.z; o.w = acc[r].w + b4.w;
            ((float4*)(out + (size_t)row * 256))[lane] = o;
        }
    }
}

// ---------------- fused attention: wave per dst node, 4-edge batches ----------------
// lane = 4 channels (float4); 16-lane group g handles edge i+g's ea/logit.
// ea lane-distributed (1 dword/lane/batch), broadcast via readlane.
template <bool CONCAT>
__global__ __launch_bounds__(256) void k_attn(
    const float* __restrict__ xl, const float* __restrict__ xr,
    const float* __restrict__ ea, const float* __restrict__ We,
    const float* __restrict__ att, const int* __restrict__ sorted,
    const int* __restrict__ srcs, const int* __restrict__ offs,
    const float* __restrict__ bias, float* __restrict__ out)
{
    int tid = threadIdx.x;
    int lane = tid & 63, wave = tid >> 6;
    float4 wr[16];
    #pragma unroll
    for (int k = 0; k < 16; ++k) wr[k] = ((const float4*)(We + k * 256))[lane];
    float4 ar = ((const float4*)att)[lane];

    int n = blockIdx.x * 4 + wave;
    if (n >= NN) return;
    int beg = offs[n], end = offs[n + 1];
    float4 xr4 = ((const float4*)(xr + (size_t)n * 256))[lane];

    float m = -INFINITY, ssum = 0.f;
    float4 acc = make_float4(0.f, 0.f, 0.f, 0.f);

    int g16 = lane >> 4;
    int k16 = lane & 15;

    float nea = 0.f;
    float4 nx0, nx1, nx2, nx3;

    auto loadbatch = [&](int i) {
        int idx = i + g16;
        if (idx > end - 1) idx = end - 1;
        int e = sorted[idx];
        int sv = srcs[idx];
        nea = ea[(size_t)e * 16 + k16];
        int s0 = __builtin_amdgcn_readlane(sv, 0);
        int s1 = __builtin_amdgcn_readlane(sv, 16);
        int s2 = __builtin_amdgcn_readlane(sv, 32);
        int s3 = __builtin_amdgcn_readlane(sv, 48);
        nx0 = ((const float4*)(xl + (size_t)s0 * 256))[lane];
        nx1 = ((const float4*)(xl + (size_t)s1 * 256))[lane];
        nx2 = ((const float4*)(xl + (size_t)s2 * 256))[lane];
        nx3 = ((const float4*)(xl + (size_t)s3 * 256))[lane];
    };

    if (beg < end) loadbatch(beg);

    for (int i = beg; i < end; i += 4) {
        float cea = nea;
        float4 x0 = nx0, x1 = nx1, x2 = nx2, x3 = nx3;
        if (i + 4 < end) loadbatch(i + 4);

        float p[4];
        float4 xs0 = x0, xs1 = x1, xs2 = x2, xs3 = x3;
        #pragma unroll
        for (int g = 0; g < 4; ++g) {
            float4 xg = (g == 0) ? xs0 : (g == 1) ? xs1 : (g == 2) ? xs2 : xs3;
            float4 em = make_float4(0.f, 0.f, 0.f, 0.f);
            #pragma unroll
            for (int k = 0; k < 16; ++k) {
                float a = rdlane(cea, g * 16 + k);
                em.x = fmaf(a, wr[k].x, em.x);
                em.y = fmaf(a, wr[k].y, em.y);
                em.z = fmaf(a, wr[k].z, em.z);
                em.w = fmaf(a, wr[k].w, em.w);
            }
            float z0 = xg.x + xr4.x + em.x;
            float z1 = xg.y + xr4.y + em.y;
            float z2 = xg.z + xr4.z + em.z;
            float z3 = xg.w + xr4.w + em.w;
            z0 = (z0 > 0.f) ? z0 : kSlope * z0;
            z1 = (z1 > 0.f) ? z1 : kSlope * z1;
            z2 = (z2 > 0.f) ? z2 : kSlope * z2;
            z3 = (z3 > 0.f) ? z3 : kSlope * z3;
            float pv = fmaf(z0, ar.x, fmaf(z1, ar.y, fmaf(z2, ar.z, z3 * ar.w)));
            pv += __shfl_xor(pv, 1, 64);
            pv += __shfl_xor(pv, 2, 64);
            pv += __shfl_xor(pv, 4, 64);
            pv += __shfl_xor(pv, 8, 64);
            p[g] = (i + g < end) ? pv : -INFINITY;
        }
        float pm = fmaxf(fmaxf(p[0], p[1]), fmaxf(p[2], p[3]));
        float mn = fmaxf(m, pm);
        float sc = __expf(m - mn);
        float w0 = __expf(p[0] - mn);
        float w1 = __expf(p[1] - mn);
        float w2 = __expf(p[2] - mn);
        float w3 = __expf(p[3] - mn);
        ssum = fmaf(ssum, sc, (w0 + w1) + (w2 + w3));
        acc.x = fmaf(acc.x, sc, fmaf(w0, x0.x, fmaf(w1, x1.x, fmaf(w2, x2.x, w3 * x3.x))));
        acc.y = fmaf(acc.y, sc, fmaf(w0, x0.y, fmaf(w1, x1.y, fmaf(w2, x2.y, w3 * x3.y))));
        acc.z = fmaf(acc.z, sc, fmaf(w0, x0.z, fmaf(w1, x1.z, fmaf(w2, x2.z, w3 * x3.z))));
        acc.w = fmaf(acc.w, sc, fmaf(w0, x0.w, fmaf(w1, x1.w, fmaf(w2, x2.w, w3 * x3.w))));
        m = mn;
    }

    float inv = 1.f / (ssum + 1e-16f);
    if (CONCAT) {
        float4 b4 = ((const float4*)bias)[lane];
        float4 o;
        o.x = fmaf(acc.x, inv, b4.x);
        o.y = fmaf(acc.y, inv, b4.y);
        o.z = fmaf(acc.z, inv, b4.z);
        o.w = fmaf(acc.w, inv, b4.w);
        ((float4*)(out + (size_t)n * 256))[lane] = o;
    } else {
        float v0 = acc.x * inv, v1 = acc.y * inv, v2 = acc.z * inv, v3 = acc.w * inv;
        v0 += __shfl_xor(v0, 16, 64); v0 += __shfl_xor(v0, 32, 64);
        v1 += __shfl_xor(v1, 16, 64); v1 += __shfl_xor(v1, 32, 64);
        v2 += __shfl_xor(v2, 16, 64); v2 += __shfl_xor(v2, 32, 64);
        v3 += __shfl_xor(v3, 16, 64); v3 += __shfl_xor(v3, 32, 64);
        if (lane < 16) {
            float4 b4 = ((const float4*)bias)[lane];
            float4 o;
            o.x = fmaf(0.25f, v0, b4.x);
            o.y = fmaf(0.25f, v1, b4.y);
            o.z = fmaf(0.25f, v2, b4.z);
            o.w = fmaf(0.25f, v3, b4.w);
            ((float4*)(out + (size_t)n * 64))[lane] = o;
        }
    }
}

// ---------------- batchnorm stats (sum, sumsq per channel) ----------------
template <int CH>
__global__ __launch_bounds__(256) void k_bn_stats(const float* __restrict__ h,
                                                  float* __restrict__ sum,
                                                  float* __restrict__ sumsq)
{
    constexpr int RP = 256 / CH;
    int tid = threadIdx.x;
    int c = tid % CH;
    int rsub = tid / CH;
    float s = 0.f, q = 0.f;
    for (int n = blockIdx.x * RP + rsub; n < NN; n += gridDim.x * RP) {
        float v = h[(size_t)n * CH + c];
        s += v; q = fmaf(v, v, q);
    }
    __shared__ float ls[256], lq[256];
    ls[tid] = s; lq[tid] = q;
    __syncthreads();
    if (tid < CH) {
        #pragma unroll
        for (int r = 1; r < RP; ++r) { s += ls[tid + r * CH]; q += lq[tid + r * CH]; }
        atomicAdd(&sum[tid], s);
        atomicAdd(&sumsq[tid], q);
    }
}

__global__ void k_bn_finalize(const float* __restrict__ sum, const float* __restrict__ sumsq,
                              const float* __restrict__ g, const float* __restrict__ beta,
                              float* __restrict__ scale, float* __restrict__ shift, int CH)
{
    int c = threadIdx.x;
    if (c >= CH) return;
    float inv_n = 1.f / (float)NN;
    float mu = sum[c] * inv_n;
    float var = sumsq[c] * inv_n - mu * mu;
    float sc = g[c] / sqrtf(var + kBnEps);
    scale[c] = sc;
    shift[c] = fmaf(-mu, sc, beta[c]);
}

// ---------------- graph mean-pool (batch is sorted) ----------------
__global__ __launch_bounds__(64) void k_pool(const float* __restrict__ h2,
                                             const float* __restrict__ scale,
                                             const float* __restrict__ shift,
                                             const int* __restrict__ batch,
                                             float* __restrict__ pooled)
{
    int lane = threadIdx.x;
    int start = blockIdx.x * 128;
    int stop = start + 128 < NN ? start + 128 : NN;
    if (start >= NN) return;
    float sc = scale[lane], sh = shift[lane];
    int curg = batch[start];
    float acc = 0.f;
    for (int n = start; n < stop; ++n) {
        int g = batch[n];
        if (g != curg) {
            atomicAdd(&pooled[(size_t)curg * 64 + lane], acc);
            acc = 0.f; curg = g;
        }
        acc += fmaf(h2[(size_t)n * 64 + lane], sc, sh);
    }
    atomicAdd(&pooled[(size_t)curg * 64 + lane], acc);
}

__global__ __launch_bounds__(256) void k_gcnt(const int* __restrict__ batch, int* __restrict__ gcnt)
{
    int n = blockIdx.x * 256 + threadIdx.x;
    if (n < NN) atomicAdd(&gcnt[batch[n]], 1);
}

// ---------------- MLP head: 64 -> 32 -> 16 -> 1 per graph ----------------
__global__ __launch_bounds__(64) void k_mlp(const float* __restrict__ pooled,
                                            const int* __restrict__ gcnt,
                                            const float* __restrict__ Wm1, const float* __restrict__ bm1,
                                            const float* __restrict__ Wm2, const float* __restrict__ bm2,
                                            const float* __restrict__ Wm3, const float* __restrict__ bm3,
                                            float* __restrict__ out)
{
    int g = blockIdx.x, lane = threadIdx.x;
    __shared__ float p[64], z1[32], z2[16];
    float cntf = fmaxf((float)gcnt[g], 1.f);
    p[lane] = pooled[(size_t)g * 64 + lane] / cntf;
    __syncthreads();
    if (lane < 32) {
        float a = bm1[lane];
        #pragma unroll
        for (int k = 0; k < 64; ++k) a = fmaf(p[k], Wm1[k * 32 + lane], a);
        z1[lane] = fmaxf(a, 0.f);
    }
    __syncthreads();
    if (lane < 16) {
        float a = bm2[lane];
        #pragma unroll
        for (int k = 0; k < 32; ++k) a = fmaf(z1[k], Wm2[k * 16 + lane], a);
        z2[lane] = fmaxf(a, 0.f);
    }
    __syncthreads();
    if (lane == 0) {
        float a = bm3[0];
        #pragma unroll
        for (int k = 0; k < 16; ++k) a = fmaf(z2[k], Wm3[k], a);
        out[g] = a;
    }
}

// ---------------- host launcher ----------------
extern "C" void kernel_launch(void* const* d_in, const int* in_sizes, int n_in,
                              void* d_out, int out_size, void* d_ws, size_t ws_size,
                              hipStream_t stream)
{
    const float* x     = (const float*)d_in[0];
    const float* ea    = (const float*)d_in[1];
    const int*   ei    = (const int*)d_in[2];
    const int*   bat   = (const int*)d_in[3];
    const float* W_in  = (const float*)d_in[4];
    const float* b_in  = (const float*)d_in[5];
    const float* Wl0   = (const float*)d_in[6];
    const float* bl0   = (const float*)d_in[7];
    const float* Wr0   = (const float*)d_in[8];
    const float* br0   = (const float*)d_in[9];
    const float* We0   = (const float*)d_in[10];
    const float* att0  = (const float*)d_in[11];
    const float* bias0 = (const float*)d_in[12];
    const float* g0    = (const float*)d_in[13];
    const float* beta0 = (const float*)d_in[14];
    const float* Wl1   = (const float*)d_in[15];
    const float* bl1   = (const float*)d_in[16];
    const float* Wr1   = (const float*)d_in[17];
    const float* br1   = (const float*)d_in[18];
    const float* We1   = (const float*)d_in[19];
    const float* att1  = (const float*)d_in[20];
    const float* bias1 = (const float*)d_in[21];
    const float* g1    = (const float*)d_in[22];
    const float* beta1 = (const float*)d_in[23];
    const float* Wm1   = (const float*)d_in[24];
    const float* bm1   = (const float*)d_in[25];
    const float* Wm2   = (const float*)d_in[26];
    const float* bm2   = (const float*)d_in[27];
    const float* Wm3   = (const float*)d_in[28];
    const float* bm3   = (const float*)d_in[29];
    const int* src = ei;
    const int* dst = ei + NE;
    float* out = (float*)d_out;

    char* p = (char*)d_ws;
    auto take = [&](size_t nbytes) -> char* {
        char* q = p;
        p += (nbytes + 255) & ~(size_t)255;
        return q;
    };
    // ---- zero zone (one memset) ----
    char* z0 = p;
    int*   hist   = (int*)take((size_t)NN * 4);
    float* bns0   = (float*)take(256 * 4);
    float* bnq0   = (float*)take(256 * 4);
    float* bns1   = (float*)take(64 * 4);
    float* bnq1   = (float*)take(64 * 4);
    float* pooled = (float*)take((size_t)NG * 64 * 4);
    int*   gcnt   = (int*)take((size_t)NG * 4);
    size_t zbytes = (size_t)(p - z0);
    // ---- rest of workspace ----
    int*   offs   = (int*)take((size_t)(NN + 1) * 4);
    int*   curs   = (int*)take((size_t)NN * 4);
    int*   sorted = (int*)take((size_t)NE * 4);
    int*   srcs   = (int*)take((size_t)NE * 4);
    float* h0     = (float*)take((size_t)NN * 64 * 4);    // reused as h2
    float* xl     = (float*)take((size_t)NN * 256 * 4);
    float* xr     = (float*)take((size_t)NN * 256 * 4);
    float* h1     = (float*)take((size_t)NN * 256 * 4);
    float* scale0 = (float*)take(256 * 4);
    float* shift0 = (float*)take(256 * 4);
    float* scale1 = (float*)take(64 * 4);
    float* shift1 = (float*)take(64 * 4);

    hipMemsetAsync(z0, 0, zbytes, stream);

    k_input_proj<<<(NN + 3) / 4, 256, 0, stream>>>(x, W_in, b_in, h0);

    k_hist<<<(NE + 255) / 256, 256, 0, stream>>>(dst, hist);
    k_scan<<<1, 1024, 0, stream>>>(hist, offs, curs);
    k_scatter<<<(NE + 255) / 256, 256, 0, stream>>>(dst, src, curs, sorted, srcs);

    // ---- GATv2 layer 0 ----
    k_linear<64, false><<<(NN + 63) / 64, 256, 0, stream>>>(h0, Wl0, bl0, nullptr, nullptr, xl);
    k_linear<64, false><<<(NN + 63) / 64, 256, 0, stream>>>(h0, Wr0, br0, nullptr, nullptr, xr);
    k_attn<true><<<(NN + 3) / 4, 256, 0, stream>>>(xl, xr, ea, We0, att0, sorted, srcs, offs, bias0, h1);
    k_bn_stats<256><<<128, 256, 0, stream>>>(h1, bns0, bnq0);
    k_bn_finalize<<<1, 256, 0, stream>>>(bns0, bnq0, g0, beta0, scale0, shift0, 256);

    // ---- GATv2 layer 1 (BN0+relu folded into linear input reads) ----
    k_linear<256, true><<<(NN + 63) / 64, 256, 0, stream>>>(h1, Wl1, bl1, scale0, shift0, xl);
    k_linear<256, true><<<(NN + 63) / 64, 256, 0, stream>>>(h1, Wr1, br1, scale0, shift0, xr);
    k_attn<false><<<(NN + 3) / 4, 256, 0, stream>>>(xl, xr, ea, We1, att1, sorted, srcs, offs, bias1, h0);
    k_bn_stats<64><<<128, 256, 0, stream>>>(h0, bns1, bnq1);
    k_bn_finalize<<<1, 64, 0, stream>>>(bns1, bnq1, g1, beta1, scale1, shift1, 64);

    // ---- pool + MLP ----
    k_pool<<<(NN + 127) / 128, 64, 0, stream>>>(h0, scale1, shift1, bat, pooled);
    k_gcnt<<<(NN + 255) / 256, 256, 0, stream>>>(bat, gcnt);
    k_mlp<<<NG, 64, 0, stream>>>(pooled, gcnt, Wm1, bm1, Wm2, bm2, Wm3, bm3, out);
}

// Round 4
// 984.078 us; speedup vs baseline: 1.7419x; 1.2868x over previous
//
#include <hip/hip_runtime.h>
#include <math.h>

constexpr int NN = 50000;
constexpr int NE = 600000;
constexpr int NG = 256;
constexpr int SB = (NN + 255) / 256;  // scan blocks = 196
constexpr float kBnEps = 1e-5f;
constexpr float kSlope = 0.2f;

__device__ __forceinline__ float rdlane(float v, int l) {
    return __builtin_bit_cast(float, __builtin_amdgcn_readlane(__builtin_bit_cast(int, v), l));
}

// DPP-based add: v += v[permuted lane] — VALU only, no LDS pipe.
template <int CTRL>
__device__ __forceinline__ float dppadd(float v) {
    int t = __builtin_amdgcn_mov_dpp(__builtin_bit_cast(int, v), CTRL, 0xF, 0xF, true);
    return v + __builtin_bit_cast(float, t);
}
// sum over each 16-lane group (all 16 lanes end with the group sum)
__device__ __forceinline__ float sum16(float v) {
    v = dppadd<0xB1>(v);    // quad_perm [1,0,3,2]
    v = dppadd<0x4E>(v);    // quad_perm [2,3,0,1]
    v = dppadd<0x141>(v);   // row_half_mirror
    v = dppadd<0x140>(v);   // row_mirror
    return v;
}

// ---------------- input projection: h0 = relu(x @ W_in + b_in) ----------------
__global__ __launch_bounds__(256) void k_input_proj(
    const float* __restrict__ x, const float* __restrict__ W,
    const float* __restrict__ b, float* __restrict__ h0)
{
    __shared__ float Wl[64 * 64];
    __shared__ float bl[64];
    int tid = threadIdx.x;
    for (int i = tid; i < 64 * 64; i += 256) Wl[i] = W[i];
    if (tid < 64) bl[tid] = b[tid];
    __syncthreads();
    int lane = tid & 63, wave = tid >> 6;
    int row = blockIdx.x * 4 + wave;
    if (row >= NN) return;
    float xv = x[(size_t)row * 64 + lane];
    float acc = bl[lane];
    #pragma unroll
    for (int k = 0; k < 64; ++k) {
        float hb = rdlane(xv, k);
        acc = fmaf(hb, Wl[k * 64 + lane], acc);
    }
    h0[(size_t)row * 64 + lane] = fmaxf(acc, 0.f);
}

// ---------------- counting sort of edges by dst ----------------
__global__ __launch_bounds__(256) void k_hist(const int* __restrict__ dst, int* __restrict__ cnt)
{
    int e = blockIdx.x * 256 + threadIdx.x;
    if (e < NE) atomicAdd(&cnt[dst[e]], 1);
}

// parallel scan, 3 kernels: per-block inclusive scan, block-sum scan, fixup
__global__ __launch_bounds__(256) void k_scanA(const int* __restrict__ cnt,
                                               int* __restrict__ offs, int* __restrict__ bsum)
{
    __shared__ int s[256];
    int tid = threadIdx.x;
    int i = blockIdx.x * 256 + tid;
    int v = (i < NN) ? cnt[i] : 0;
    s[tid] = v;
    __syncthreads();
    #pragma unroll
    for (int d = 1; d < 256; d <<= 1) {
        int u = (tid >= d) ? s[tid - d] : 0;
        __syncthreads();
        s[tid] += u;
        __syncthreads();
    }
    if (i < NN) offs[i] = s[tid];           // block-local inclusive
    if (tid == 255) bsum[blockIdx.x] = s[255];
}

__global__ __launch_bounds__(256) void k_scanB(int* __restrict__ bsum)
{
    __shared__ int s[256];
    int t = threadIdx.x;
    int v = (t < SB) ? bsum[t] : 0;
    s[t] = v;
    __syncthreads();
    #pragma unroll
    for (int d = 1; d < 256; d <<= 1) {
        int u = (t >= d) ? s[t - d] : 0;
        __syncthreads();
        s[t] += u;
        __syncthreads();
    }
    if (t < SB) bsum[t] = s[t];             // inclusive over block sums
}

__global__ __launch_bounds__(256) void k_scanC(const int* __restrict__ cnt,
                                               const int* __restrict__ bsum,
                                               int* __restrict__ offs, int* __restrict__ cur)
{
    int i = blockIdx.x * 256 + threadIdx.x;
    if (i > NN) return;
    if (i == NN) { offs[NN] = NE; return; }
    int pre = (blockIdx.x > 0) ? bsum[blockIdx.x - 1] : 0;
    int v = offs[i] - cnt[i] + pre;         // global exclusive
    offs[i] = v;
    cur[i] = v;
}

__global__ __launch_bounds__(256) void k_scatter(const int* __restrict__ dst,
                                                 const int* __restrict__ src,
                                                 int* __restrict__ cur,
                                                 int* __restrict__ sorted,
                                                 int* __restrict__ srcs)
{
    int e = blockIdx.x * 256 + threadIdx.x;
    if (e < NE) {
        int p = atomicAdd(&cur[dst[e]], 1);
        sorted[p] = e;
        srcs[p] = src[e];
    }
}

// graph boundaries in sorted batch: gstart[g] = first row with batch >= g
__global__ __launch_bounds__(256) void k_gbounds(const int* __restrict__ batch,
                                                 int* __restrict__ gstart)
{
    int g = threadIdx.x;
    int lo = 0, hi = NN;
    while (lo < hi) {
        int mid = (lo + hi) >> 1;
        if (batch[mid] < g) lo = mid + 1; else hi = mid;
    }
    gstart[g] = lo;
    if (g == 0) gstart[NG] = NN;
}

// ---------------- generic linear: out[n][0..255] = f(h[n]) @ W + b ----------------
template <int K, bool BN>
__global__ __launch_bounds__(256) void k_linear(
    const float* __restrict__ h, const float* __restrict__ W,
    const float* __restrict__ bvec, const float* __restrict__ scale,
    const float* __restrict__ shift, float* __restrict__ out)
{
    __shared__ float Wl[32 * 256];  // 32 KB
    int tid = threadIdx.x;
    int lane = tid & 63, wave = tid >> 6;
    int row0 = blockIdx.x * 64 + wave * 16;
    int half = lane >> 5;
    int kl = lane & 31;
    float4 acc[16];
    #pragma unroll
    for (int r = 0; r < 16; ++r) acc[r] = make_float4(0.f, 0.f, 0.f, 0.f);

    for (int kt = 0; kt < K / 32; ++kt) {
        __syncthreads();
        for (int i = tid * 4; i < 32 * 256; i += 1024) {
            *(float4*)(Wl + i) = *(const float4*)(W + (size_t)kt * 32 * 256 + i);
        }
        float hreg[8];
        float sc = 1.f, sh = 0.f;
        if (BN) { sc = scale[kt * 32 + kl]; sh = shift[kt * 32 + kl]; }
        #pragma unroll
        for (int r = 0; r < 8; ++r) {
            int row = row0 + 2 * r + half;
            if (row >= NN) row = NN - 1;
            float v = h[(size_t)row * K + kt * 32 + kl];
            if (BN) v = fmaxf(fmaf(v, sc, sh), 0.f);
            hreg[r] = v;
        }
        __syncthreads();
        #pragma unroll 8
        for (int k = 0; k < 32; ++k) {
            float4 w4 = *(const float4*)&Wl[k * 256 + 4 * lane];
            #pragma unroll
            for (int r = 0; r < 8; ++r) {
                float h0 = rdlane(hreg[r], k);
                float h1 = rdlane(hreg[r], 32 + k);
                acc[2 * r].x = fmaf(h0, w4.x, acc[2 * r].x);
                acc[2 * r].y = fmaf(h0, w4.y, acc[2 * r].y);
                acc[2 * r].z = fmaf(h0, w4.z, acc[2 * r].z);
                acc[2 * r].w = fmaf(h0, w4.w, acc[2 * r].w);
                acc[2 * r + 1].x = fmaf(h1, w4.x, acc[2 * r + 1].x);
                acc[2 * r + 1].y = fmaf(h1, w4.y, acc[2 * r + 1].y);
                acc[2 * r + 1].z = fmaf(h1, w4.z, acc[2 * r + 1].z);
                acc[2 * r + 1].w = fmaf(h1, w4.w, acc[2 * r + 1].w);
            }
        }
    }
    float4 b4 = ((const float4*)bvec)[lane];
    #pragma unroll
    for (int r = 0; r < 16; ++r) {
        int row = row0 + r;
        if (row < NN) {
            float4 o;
            o.x = acc[r].x + b4.x; o.y = acc[r].y + b4.y;
            o.z = acc[r].z + b4.z; o.w = acc[r].w + b4.w;
            ((float4*)(out + (size_t)row * 256))[lane] = o;
        }
    }
}

// ---------------- fused attention: wave per dst node, 4-edge batches ----------------
template <bool CONCAT>
__global__ __launch_bounds__(256) void k_attn(
    const float* __restrict__ xl, const float* __restrict__ xr,
    const float* __restrict__ ea, const float* __restrict__ We,
    const float* __restrict__ att, const int* __restrict__ sorted,
    const int* __restrict__ srcs, const int* __restrict__ offs,
    const float* __restrict__ bias, float* __restrict__ out)
{
    int tid = threadIdx.x;
    int lane = tid & 63, wave = tid >> 6;
    float4 wr[16];
    #pragma unroll
    for (int k = 0; k < 16; ++k) wr[k] = ((const float4*)(We + k * 256))[lane];
    float4 ar = ((const float4*)att)[lane];

    int n = blockIdx.x * 4 + wave;
    if (n >= NN) return;
    int beg = offs[n], end = offs[n + 1];
    float4 xr4 = ((const float4*)(xr + (size_t)n * 256))[lane];

    float m = -INFINITY, ssum = 0.f;
    float4 acc = make_float4(0.f, 0.f, 0.f, 0.f);

    int g16 = lane >> 4;
    int k16 = lane & 15;

    float nea = 0.f;
    float4 nx0, nx1, nx2, nx3;

    auto loadbatch = [&](int i) {
        int idx = i + g16;
        if (idx > end - 1) idx = end - 1;
        int e = sorted[idx];
        int sv = srcs[idx];
        nea = ea[(size_t)e * 16 + k16];
        int s0 = __builtin_amdgcn_readlane(sv, 0);
        int s1 = __builtin_amdgcn_readlane(sv, 16);
        int s2 = __builtin_amdgcn_readlane(sv, 32);
        int s3 = __builtin_amdgcn_readlane(sv, 48);
        nx0 = ((const float4*)(xl + (size_t)s0 * 256))[lane];
        nx1 = ((const float4*)(xl + (size_t)s1 * 256))[lane];
        nx2 = ((const float4*)(xl + (size_t)s2 * 256))[lane];
        nx3 = ((const float4*)(xl + (size_t)s3 * 256))[lane];
    };

    if (beg < end) loadbatch(beg);

    for (int i = beg; i < end; i += 4) {
        float cea = nea;
        float4 x0 = nx0, x1 = nx1, x2 = nx2, x3 = nx3;
        if (i + 4 < end) loadbatch(i + 4);

        float p[4];
        #pragma unroll
        for (int g = 0; g < 4; ++g) {
            float4 xg = (g == 0) ? x0 : (g == 1) ? x1 : (g == 2) ? x2 : x3;
            float4 em = xr4;  // fold xr into accumulator init
            #pragma unroll
            for (int k = 0; k < 16; ++k) {
                float a = rdlane(cea, g * 16 + k);
                em.x = fmaf(a, wr[k].x, em.x);
                em.y = fmaf(a, wr[k].y, em.y);
                em.z = fmaf(a, wr[k].z, em.z);
                em.w = fmaf(a, wr[k].w, em.w);
            }
            float z0 = xg.x + em.x;
            float z1 = xg.y + em.y;
            float z2 = xg.z + em.z;
            float z3 = xg.w + em.w;
            z0 = (z0 > 0.f) ? z0 : kSlope * z0;
            z1 = (z1 > 0.f) ? z1 : kSlope * z1;
            z2 = (z2 > 0.f) ? z2 : kSlope * z2;
            z3 = (z3 > 0.f) ? z3 : kSlope * z3;
            float pv = fmaf(z0, ar.x, fmaf(z1, ar.y, fmaf(z2, ar.z, z3 * ar.w)));
            pv = sum16(pv);  // DPP reduce over the 16-lane head group (VALU only)
            p[g] = (i + g < end) ? pv : -INFINITY;
        }
        float pm = fmaxf(fmaxf(p[0], p[1]), fmaxf(p[2], p[3]));
        float mn = fmaxf(m, pm);
        float sc = __expf(m - mn);
        float w0 = __expf(p[0] - mn);
        float w1 = __expf(p[1] - mn);
        float w2 = __expf(p[2] - mn);
        float w3 = __expf(p[3] - mn);
        ssum = fmaf(ssum, sc, (w0 + w1) + (w2 + w3));
        acc.x = fmaf(acc.x, sc, fmaf(w0, x0.x, fmaf(w1, x1.x, fmaf(w2, x2.x, w3 * x3.x))));
        acc.y = fmaf(acc.y, sc, fmaf(w0, x0.y, fmaf(w1, x1.y, fmaf(w2, x2.y, w3 * x3.y))));
        acc.z = fmaf(acc.z, sc, fmaf(w0, x0.z, fmaf(w1, x1.z, fmaf(w2, x2.z, w3 * x3.z))));
        acc.w = fmaf(acc.w, sc, fmaf(w0, x0.w, fmaf(w1, x1.w, fmaf(w2, x2.w, w3 * x3.w))));
        m = mn;
    }

    float inv = 1.f / (ssum + 1e-16f);
    if (CONCAT) {
        float4 b4 = ((const float4*)bias)[lane];
        float4 o;
        o.x = fmaf(acc.x, inv, b4.x);
        o.y = fmaf(acc.y, inv, b4.y);
        o.z = fmaf(acc.z, inv, b4.z);
        o.w = fmaf(acc.w, inv, b4.w);
        ((float4*)(out + (size_t)n * 256))[lane] = o;
    } else {
        float v0 = acc.x * inv, v1 = acc.y * inv, v2 = acc.z * inv, v3 = acc.w * inv;
        v0 += __shfl_xor(v0, 16, 64); v0 += __shfl_xor(v0, 32, 64);
        v1 += __shfl_xor(v1, 16, 64); v1 += __shfl_xor(v1, 32, 64);
        v2 += __shfl_xor(v2, 16, 64); v2 += __shfl_xor(v2, 32, 64);
        v3 += __shfl_xor(v3, 16, 64); v3 += __shfl_xor(v3, 32, 64);
        if (lane < 16) {
            float4 b4 = ((const float4*)bias)[lane];
            float4 o;
            o.x = fmaf(0.25f, v0, b4.x);
            o.y = fmaf(0.25f, v1, b4.y);
            o.z = fmaf(0.25f, v2, b4.z);
            o.w = fmaf(0.25f, v3, b4.w);
            ((float4*)(out + (size_t)n * 64))[lane] = o;
        }
    }
}

// ---------------- batchnorm stats (sum, sumsq per channel) ----------------
template <int CH>
__global__ __launch_bounds__(256) void k_bn_stats(const float* __restrict__ h,
                                                  float* __restrict__ sum,
                                                  float* __restrict__ sumsq)
{
    constexpr int RP = 256 / CH;
    int tid = threadIdx.x;
    int c = tid % CH;
    int rsub = tid / CH;
    float s = 0.f, q = 0.f;
    for (int n = blockIdx.x * RP + rsub; n < NN; n += gridDim.x * RP) {
        float v = h[(size_t)n * CH + c];
        s += v; q = fmaf(v, v, q);
    }
    __shared__ float ls[256], lq[256];
    ls[tid] = s; lq[tid] = q;
    __syncthreads();
    if (tid < CH) {
        #pragma unroll
        for (int r = 1; r < RP; ++r) { s += ls[tid + r * CH]; q += lq[tid + r * CH]; }
        atomicAdd(&sum[tid], s);
        atomicAdd(&sumsq[tid], q);
    }
}

__global__ void k_bn_finalize(const float* __restrict__ sum, const float* __restrict__ sumsq,
                              const float* __restrict__ g, const float* __restrict__ beta,
                              float* __restrict__ scale, float* __restrict__ shift, int CH)
{
    int c = threadIdx.x;
    if (c >= CH) return;
    float inv_n = 1.f / (float)NN;
    float mu = sum[c] * inv_n;
    float var = sumsq[c] * inv_n - mu * mu;
    float sc = g[c] / sqrtf(var + kBnEps);
    scale[c] = sc;
    shift[c] = fmaf(-mu, sc, beta[c]);
}

// ---------------- fused BN + mean-pool + MLP head: one block per graph ----------------
__global__ __launch_bounds__(256) void k_pool_mlp(
    const float* __restrict__ h2, const float* __restrict__ scale,
    const float* __restrict__ shift, const int* __restrict__ gstart,
    const float* __restrict__ Wm1, const float* __restrict__ bm1,
    const float* __restrict__ Wm2, const float* __restrict__ bm2,
    const float* __restrict__ Wm3, const float* __restrict__ bm3,
    float* __restrict__ out)
{
    int g = blockIdx.x, tid = threadIdx.x;
    int lane = tid & 63, wave = tid >> 6;
    int s = gstart[g], e = gstart[g + 1];
    float sc = scale[lane], sh = shift[lane];
    float acc = 0.f;
    for (int n = s + wave; n < e; n += 4)
        acc += fmaf(h2[(size_t)n * 64 + lane], sc, sh);
    __shared__ float red[4][64];
    red[wave][lane] = acc;
    __syncthreads();
    __shared__ float p[64], z1[32], z2[16];
    if (tid < 64) {
        float cnt = (float)(e - s);
        float a = red[0][tid] + red[1][tid] + red[2][tid] + red[3][tid];
        p[tid] = a / fmaxf(cnt, 1.f);
    }
    __syncthreads();
    if (tid < 32) {
        float a = bm1[tid];
        #pragma unroll
        for (int k = 0; k < 64; ++k) a = fmaf(p[k], Wm1[k * 32 + tid], a);
        z1[tid] = fmaxf(a, 0.f);
    }
    __syncthreads();
    if (tid < 16) {
        float a = bm2[tid];
        #pragma unroll
        for (int k = 0; k < 32; ++k) a = fmaf(z1[k], Wm2[k * 16 + tid], a);
        z2[tid] = fmaxf(a, 0.f);
    }
    __syncthreads();
    if (tid == 0) {
        float a = bm3[0];
        #pragma unroll
        for (int k = 0; k < 16; ++k) a = fmaf(z2[k], Wm3[k], a);
        out[g] = a;
    }
}

// ---------------- host launcher ----------------
extern "C" void kernel_launch(void* const* d_in, const int* in_sizes, int n_in,
                              void* d_out, int out_size, void* d_ws, size_t ws_size,
                              hipStream_t stream)
{
    const float* x     = (const float*)d_in[0];
    const float* ea    = (const float*)d_in[1];
    const int*   ei    = (const int*)d_in[2];
    const int*   bat   = (const int*)d_in[3];
    const float* W_in  = (const float*)d_in[4];
    const float* b_in  = (const float*)d_in[5];
    const float* Wl0   = (const float*)d_in[6];
    const float* bl0   = (const float*)d_in[7];
    const float* Wr0   = (const float*)d_in[8];
    const float* br0   = (const float*)d_in[9];
    const float* We0   = (const float*)d_in[10];
    const float* att0  = (const float*)d_in[11];
    const float* bias0 = (const float*)d_in[12];
    const float* g0    = (const float*)d_in[13];
    const float* beta0 = (const float*)d_in[14];
    const float* Wl1   = (const float*)d_in[15];
    const float* bl1   = (const float*)d_in[16];
    const float* Wr1   = (const float*)d_in[17];
    const float* br1   = (const float*)d_in[18];
    const float* We1   = (const float*)d_in[19];
    const float* att1  = (const float*)d_in[20];
    const float* bias1 = (const float*)d_in[21];
    const float* g1    = (const float*)d_in[22];
    const float* beta1 = (const float*)d_in[23];
    const float* Wm1   = (const float*)d_in[24];
    const float* bm1   = (const float*)d_in[25];
    const float* Wm2   = (const float*)d_in[26];
    const float* bm2   = (const float*)d_in[27];
    const float* Wm3   = (const float*)d_in[28];
    const float* bm3   = (const float*)d_in[29];
    const int* src = ei;
    const int* dst = ei + NE;
    float* out = (float*)d_out;

    char* p = (char*)d_ws;
    auto take = [&](size_t nbytes) -> char* {
        char* q = p;
        p += (nbytes + 255) & ~(size_t)255;
        return q;
    };
    // ---- zero zone (one memset) ----
    char* z0 = p;
    int*   hist   = (int*)take((size_t)NN * 4);
    float* bns0   = (float*)take(256 * 4);
    float* bnq0   = (float*)take(256 * 4);
    float* bns1   = (float*)take(64 * 4);
    float* bnq1   = (float*)take(64 * 4);
    size_t zbytes = (size_t)(p - z0);
    // ---- rest of workspace ----
    int*   offs   = (int*)take((size_t)(NN + 1) * 4);
    int*   curs   = (int*)take((size_t)NN * 4);
    int*   bsum   = (int*)take((size_t)SB * 4);
    int*   gstart = (int*)take((size_t)(NG + 1) * 4);
    int*   sorted = (int*)take((size_t)NE * 4);
    int*   srcs   = (int*)take((size_t)NE * 4);
    float* h0     = (float*)take((size_t)NN * 64 * 4);    // reused as h2
    float* xl     = (float*)take((size_t)NN * 256 * 4);
    float* xr     = (float*)take((size_t)NN * 256 * 4);
    float* h1     = (float*)take((size_t)NN * 256 * 4);
    float* scale0 = (float*)take(256 * 4);
    float* shift0 = (float*)take(256 * 4);
    float* scale1 = (float*)take(64 * 4);
    float* shift1 = (float*)take(64 * 4);

    hipMemsetAsync(z0, 0, zbytes, stream);

    k_input_proj<<<(NN + 3) / 4, 256, 0, stream>>>(x, W_in, b_in, h0);

    k_hist<<<(NE + 255) / 256, 256, 0, stream>>>(dst, hist);
    k_scanA<<<SB, 256, 0, stream>>>(hist, offs, bsum);
    k_scanB<<<1, 256, 0, stream>>>(bsum);
    k_scanC<<<SB, 256, 0, stream>>>(hist, bsum, offs, curs);
    k_scatter<<<(NE + 255) / 256, 256, 0, stream>>>(dst, src, curs, sorted, srcs);
    k_gbounds<<<1, 256, 0, stream>>>(bat, gstart);

    // ---- GATv2 layer 0 ----
    k_linear<64, false><<<(NN + 63) / 64, 256, 0, stream>>>(h0, Wl0, bl0, nullptr, nullptr, xl);
    k_linear<64, false><<<(NN + 63) / 64, 256, 0, stream>>>(h0, Wr0, br0, nullptr, nullptr, xr);
    k_attn<true><<<(NN + 3) / 4, 256, 0, stream>>>(xl, xr, ea, We0, att0, sorted, srcs, offs, bias0, h1);
    k_bn_stats<256><<<256, 256, 0, stream>>>(h1, bns0, bnq0);
    k_bn_finalize<<<1, 256, 0, stream>>>(bns0, bnq0, g0, beta0, scale0, shift0, 256);

    // ---- GATv2 layer 1 (BN0+relu folded into linear input reads) ----
    k_linear<256, true><<<(NN + 63) / 64, 256, 0, stream>>>(h1, Wl1, bl1, scale0, shift0, xl);
    k_linear<256, true><<<(NN + 63) / 64, 256, 0, stream>>>(h1, Wr1, br1, scale0, shift0, xr);
    k_attn<false><<<(NN + 3) / 4, 256, 0, stream>>>(xl, xr, ea, We1, att1, sorted, srcs, offs, bias1, h0);
    k_bn_stats<64><<<256, 256, 0, stream>>>(h0, bns1, bnq1);
    k_bn_finalize<<<1, 64, 0, stream>>>(bns1, bnq1, g1, beta1, scale1, shift1, 64);

    // ---- fused BN + pool + MLP ----
    k_pool_mlp<<<NG, 256, 0, stream>>>(h0, scale1, shift1, gstart,
                                       Wm1, bm1, Wm2, bm2, Wm3, bm3, out);
}